// Round 4
// baseline (1507.394 us; speedup 1.0000x reference)
//
#include <hip/hip_runtime.h>
#include <hip/hip_bf16.h>
#include <math.h>

#define SEQ_LEN 128
#define BATCH   32
#define T       32
#define TT      (T*T)     // 1024
#define TTT     (T*T*T)   // 32768
#define START   30
#define END     31
#define NSLOT   3
#define NPAIR   63

typedef unsigned long long u64;

__device__ __forceinline__ u64 ald64(const u64* p) {
    return __hip_atomic_load(p, __ATOMIC_RELAXED, __HIP_MEMORY_SCOPE_AGENT);
}
__device__ __forceinline__ void astf(float* p, float v) {
    __hip_atomic_store(p, v, __ATOMIC_RELAXED, __HIP_MEMORY_SCOPE_AGENT);
}

#define WAITV(n) asm volatile("s_waitcnt vmcnt(" #n ")" ::: "memory")
#define LGKM0()  do { asm volatile("s_waitcnt lgkmcnt(0)" ::: "memory"); \
                      __builtin_amdgcn_sched_barrier(0); } while (0)

__device__ __forceinline__ void gload_lds16(const float* g, float* l) {
    __builtin_amdgcn_global_load_lds(
        (const __attribute__((address_space(1))) unsigned int*)(const void*)g,
        (__attribute__((address_space(3))) unsigned int*)(void*)l,
        16, 0, 0);
}

// ---------------------------------------------------------------------------
// Kernel 1: tg_energy gather. ws[0..15] <- per-block partial sums.
// ---------------------------------------------------------------------------
__global__ __launch_bounds__(256) void tg_kernel(const float* __restrict__ scores,
                                                 const int*   __restrict__ target,
                                                 const int*   __restrict__ mask,
                                                 float*       __restrict__ ws) {
    int idx = blockIdx.x * 256 + threadIdx.x;   // idx = s*BATCH + b
    float v = 0.0f;
    if (mask[idx] != 0) {
        v = scores[(size_t)idx * TTT + target[idx]];
    }
    #pragma unroll
    for (int off = 32; off > 0; off >>= 1)
        v += __shfl_down(v, off, 64);
    __shared__ float partial[4];
    int wave = threadIdx.x >> 6;
    int lane = threadIdx.x & 63;
    if (lane == 0) partial[wave] = v;
    __syncthreads();
    if (threadIdx.x == 0)
        ws[blockIdx.x] = partial[0] + partial[1] + partial[2] + partial[3];
}

// ---------------------------------------------------------------------------
// Kernel 2: init. Qbuf[b][1][i*32+j] = exp(part_1[i,j]) (linear domain, m=0).
// Zeros per-pair counters (replay safety; graph replays re-run this).
// ---------------------------------------------------------------------------
__global__ __launch_bounds__(1024) void init_fused(const float* __restrict__ scores,
                                                   float* __restrict__ Qbuf,
                                                   int*   __restrict__ ctr) {
    int b = blockIdx.x, tid = threadIdx.x;
    int x = tid >> 5, y = tid & 31;   // x = i, y = j
    float p1 = scores[(size_t)(0*BATCH + b)*TTT + START*TT + START*T + x];
    float s1 = scores[(size_t)(1*BATCH + b)*TTT + START*TT + x*T + y];
    float* base = Qbuf + (size_t)b * 2048;
    base[1024 + tid] = __expf(p1 + s1);   // parity 1 <- Q_1
    base[tid] = 0.0f;                     // parity 0 hygiene
    if (tid < NPAIR) ctr[tid*BATCH + b] = 0;
}

// ---------------------------------------------------------------------------
// Kernel 3: fused-pair distributed scan.
// 256 blocks = 32 batches x 8 groups; 384 threads = 4 compute + 2 streamer
// waves. Pair p = steps (t0=2+2p, t1=t0+1). Block g owns k in [4g,4g+4).
//   phase1: I[j,k'] = sum_i Q[i,j] * exp(s_t0[i,j,4g+k'] - 4)
//   phase2: O[4g+w,l] = sum_j I[j,w] * exp(s_t1[j,4g+w,l] - 4)
// Exchange: 512B contiguous publish per block + one release fetch_add;
// consumers spin one counter word (==8) then bulk-read 4KB.
// ---------------------------------------------------------------------------
__global__ __launch_bounds__(384, 1) void scan_fused(const float* __restrict__ scores,
                                                     const int*   __restrict__ maskI,
                                                     float*       __restrict__ Qbuf,
                                                     int*         __restrict__ ctr) {
    const int bid  = blockIdx.x;
    const int b    = bid & (BATCH - 1);
    const int gq   = bid >> 5;
    const int tid  = threadIdx.x;
    const int w    = tid >> 6;
    const int lane = tid & 63;

    __shared__ float slab[NSLOT][8192];   // 96 KB: [slot][ A(4096) | B(4096) ]
    __shared__ float Qld[1024];           // staged previous Q, [i*32+j]
    __shared__ float Ild[128];            // intermediate, [j*4+k']
    __shared__ int   lmask[SEQ_LEN];
    __shared__ int   tflag[2][NSLOT];     // streamer tile-arrival flags
    __shared__ int   vdoneA[4*NSLOT];     // consumer slab-done flags
    __shared__ int   xf[4], qf[4], ifl[4], pf[4];

    if (tid < SEQ_LEN) lmask[tid] = maskI[tid*BATCH + b];
    if (tid < NSLOT) { tflag[0][tid] = -1; tflag[1][tid] = -1; }
    if (tid < 4*NSLOT) vdoneA[tid] = -1;
    if (tid < 4) { xf[tid] = -1; qf[tid] = -1; ifl[tid] = -1; pf[tid] = -1; }
    __syncthreads();

    volatile int* vtf0 = tflag[0];
    volatile int* vtf1 = tflag[1];
    volatile int* vvd  = vdoneA;
    volatile int* vxf  = xf;
    volatile int* vqf  = qf;
    volatile int* vif  = ifl;
    volatile int* vpf  = pf;

    if (w >= 4) {
        // ------------------------- streamer wave -------------------------
        const int s = w - 4;
        auto issue_pair = [&](int p) {
            const int slot = p % NSLOT;
            const int t0 = 2 + 2*p, t1 = t0 + 1;
            const int a0 = lmask[t0], a1 = lmask[t1];
            const int tB = a1 ? t1 : t0;
            const float* baseB = scores + ((size_t)tB*BATCH + b)*TTT;
            const bool fused = (a0 != 0) && (a1 != 0);
            const float* baseA = fused ? scores + ((size_t)t0*BATCH + b)*TTT : baseB;
            float* ls = &slab[slot][0];
            #pragma unroll
            for (int n = 0; n < 8; ++n) {
                const int u = s*512 + n*64 + lane;
                const float* ga = fused
                    ? (baseA + (size_t)(u >> 5)*TT + (size_t)(u & 31)*T + 4*gq)   // strided k-chunk
                    : (baseA + (size_t)(u >> 5)*TT + 128*gq + (u & 31)*4);        // dummy (contig)
                gload_lds16(ga, ls + (s*512 + n*64)*4);
            }
            #pragma unroll
            for (int n = 0; n < 8; ++n) {
                const int u = s*512 + n*64 + lane;
                const float* gb = baseB + (size_t)(u >> 5)*TT + 128*gq + (u & 31)*4;
                gload_lds16(gb, ls + 4096 + (s*512 + n*64)*4);
            }
        };
        issue_pair(0); issue_pair(1); issue_pair(2);   // 48 loads in flight
        for (int p = 0; p < NPAIR; ++p) {
            if (p <= 60)      WAITV(32);   // pair p's 16 loads retired
            else if (p == 61) WAITV(16);
            else              WAITV(0);
            __builtin_amdgcn_sched_barrier(0);
            if (lane == 0) ((volatile int*)tflag[s])[p % NSLOT] = p;
            if (p + 3 < NPAIR) {
                const int slot = p % NSLOT;   // slot reused by pair p+3
                for (;;) {
                    bool ok = (vvd[0*NSLOT+slot] >= p) && (vvd[1*NSLOT+slot] >= p)
                           && (vvd[2*NSLOT+slot] >= p) && (vvd[3*NSLOT+slot] >= p);
                    if (ok) break;
                    __builtin_amdgcn_s_sleep(2);
                }
                issue_pair(p + 3);
            }
        }
    } else {
        // ------------------------- compute wave -------------------------
        const int h  = lane >> 5;
        const int jj = (lane >> 2) & 7;
        const int kp = lane & 3;
        const int l  = lane & 31;
        float* Qme = Qbuf + (size_t)b * 2048;

        for (int p = 0; p < NPAIR; ++p) {
            const int slot = p % NSLOT;
            const int t0 = 2 + 2*p, t1 = t0 + 1;
            const int a0 = lmask[t0], a1 = lmask[t1];

            // 1. wait tile (prefetched; usually immediate)
            while (!(vtf0[slot] >= p && vtf1[slot] >= p)) {}
            asm volatile("" ::: "memory");

            // 2. exp-transform this wave's quarter of the slot (off-chain)
            {
                float* base = &slab[slot][0] + w*2048 + lane*4;
                #pragma unroll
                for (int q = 0; q < 8; ++q) {
                    float4 v = *(float4*)(base + q*256);
                    v.x = __expf(v.x - 4.0f); v.y = __expf(v.y - 4.0f);
                    v.z = __expf(v.z - 4.0f); v.w = __expf(v.w - 4.0f);
                    *(float4*)(base + q*256) = v;
                }
            }
            LGKM0();
            if (lane == 0) vxf[w] = p;

            // 3. counter spin for previous pair, then bulk-read Q quarter
            if (p > 0) {
                const int* cp = ctr + (p-1)*BATCH + b;
                while (__hip_atomic_load(cp, __ATOMIC_RELAXED, __HIP_MEMORY_SCOPE_AGENT) < 8) {}
                (void)__hip_atomic_load(cp, __ATOMIC_ACQUIRE, __HIP_MEMORY_SCOPE_AGENT);
            }
            {
                const float* qsrc = Qme + (size_t)((p+1)&1)*1024 + w*256 + lane*4;
                u64 qa = ald64((const u64*)qsrc);
                u64 qb = ald64((const u64*)(qsrc + 2));
                *(u64*)&Qld[w*256 + lane*4]     = qa;
                *(u64*)&Qld[w*256 + lane*4 + 2] = qb;
            }
            LGKM0();
            if (lane == 0) vqf[w] = p;
            for (;;) {
                bool ok = true;
                #pragma unroll
                for (int q = 0; q < 4; ++q) ok = ok && (vxf[q] >= p) && (vqf[q] >= p);
                if (ok) break;
            }
            asm volatile("" ::: "memory");

            // 4. phases
            float val;
            if (a0 && a1) {
                const int j1 = 8*w + jj;
                float acc = 0.0f;
                #pragma unroll
                for (int m = 0; m < 16; ++m) {
                    const int i = h*16 + m;
                    acc = fmaf(Qld[i*32 + j1], slab[slot][i*128 + j1*4 + kp], acc);
                }
                acc += __shfl_xor(acc, 32, 64);
                if (lane < 32) Ild[32*w + lane] = acc;
                LGKM0();
                if (lane == 0) vif[w] = p;
                for (;;) {
                    bool ok = true;
                    #pragma unroll
                    for (int q = 0; q < 4; ++q) ok = ok && (vif[q] >= p);
                    if (ok) break;
                }
                asm volatile("" ::: "memory");
                float acc2 = 0.0f;
                #pragma unroll
                for (int m = 0; m < 16; ++m) {
                    const int j = h*16 + m;
                    acc2 = fmaf(Ild[j*4 + w], slab[slot][4096 + j*128 + w*32 + l], acc2);
                }
                acc2 += __shfl_xor(acc2, 32, 64);
                val = acc2;
            } else if (a0 || a1) {
                const int kabs = 4*gq + w;
                float acc2 = 0.0f;
                #pragma unroll
                for (int m = 0; m < 16; ++m) {
                    const int i = h*16 + m;
                    acc2 = fmaf(Qld[i*32 + kabs], slab[slot][4096 + i*128 + w*32 + l], acc2);
                }
                acc2 += __shfl_xor(acc2, 32, 64);
                val = acc2;
            } else {
                val = Qld[(4*gq + w)*32 + l];
            }

            // 5. slab reads done -> release slot for streamer prefetch
            LGKM0();
            if (lane == 0) vvd[w*NSLOT + slot] = p;

            // 6. publish 32 contiguous floats, then signal
            float* Qout = Qme + (size_t)(p & 1)*1024;
            if (lane < 32) astf(Qout + (4*gq + w)*32 + l, val);
            WAITV(0);
            __builtin_amdgcn_sched_barrier(0);
            if (lane == 0) vpf[w] = p;
            if (tid == 0) {
                for (;;) {
                    bool ok = (vpf[0] >= p) && (vpf[1] >= p) && (vpf[2] >= p) && (vpf[3] >= p);
                    if (ok) break;
                }
                __hip_atomic_fetch_add(ctr + p*BATCH + b, 1,
                                       __ATOMIC_RELEASE, __HIP_MEMORY_SCOPE_AGENT);
            }
        }
    }
}

// ---------------------------------------------------------------------------
// Kernel 4: finalize. part_127[END,END] = 4*(#active steps) + log(Q[END,END]).
// ---------------------------------------------------------------------------
__global__ void finalize_fused(const float* __restrict__ ws,
                               const float* __restrict__ Qbuf,
                               const int*   __restrict__ mask,
                               float*       __restrict__ out) {
    if (threadIdx.x == 0) {
        float tg = 0.0f, z = 0.0f;
        #pragma unroll
        for (int i = 0; i < 16; ++i) tg += ws[i];
        for (int b = 0; b < BATCH; ++b) {
            int cnt = 0;
            for (int t = 2; t < SEQ_LEN; ++t) cnt += (mask[t*BATCH + b] != 0);
            float qv = Qbuf[(size_t)b*2048 + END*T + END];   // parity 0 (pair 62)
            z += 4.0f * (float)cnt + logf(qv);
        }
        out[0] = (z - tg) / (float)BATCH;
    }
}

// ---------------------------------------------------------------------------
// Fallback path (small ws): round-1 single-block-per-batch scan.
// ---------------------------------------------------------------------------
__global__ __launch_bounds__(1024) void scan_simple(const float* __restrict__ scores,
                                                    const int*   __restrict__ mask,
                                                    float*       __restrict__ ws) {
    const int b   = blockIdx.x;
    const int tid = threadIdx.x;
    const int j   = tid >> 5;
    __shared__ float pA[TT];
    __shared__ float pB[TT];
    {
        int i  = tid >> 5;
        int jjy = tid & 31;
        float p1 = scores[((size_t)(0*BATCH + b)*T + START)*TT + START*T + i];
        float s1 = scores[((size_t)(1*BATCH + b)*T + START)*TT + i*T + jjy];
        pA[tid] = p1 + s1;
    }
    __syncthreads();
    float* cur = pA;
    float* nxt = pB;
    for (int t = 2; t < SEQ_LEN; ++t) {
        const float* __restrict__ sp = scores + (size_t)(t*BATCH + b)*TTT + tid;
        float buf[T];
        #pragma unroll
        for (int i = 0; i < T; ++i) buf[i] = sp[(size_t)i * TT];
        #pragma unroll
        for (int i = 0; i < T; ++i) buf[i] += cur[i*T + j];
        float m = buf[0];
        #pragma unroll
        for (int i = 1; i < T; ++i) m = fmaxf(m, buf[i]);
        float ssum = 0.0f;
        #pragma unroll
        for (int i = 0; i < T; ++i) ssum += __expf(buf[i] - m);
        float newv = m + __logf(ssum);
        if (mask[t*BATCH + b] == 0) newv = cur[tid];
        nxt[tid] = newv;
        __syncthreads();
        float* tmp = cur; cur = nxt; nxt = tmp;
    }
    if (tid == 0) ws[16 + b] = cur[END*T + END];
}

__global__ void finalize_simple(const float* __restrict__ ws, float* __restrict__ out) {
    if (threadIdx.x == 0) {
        float tg = 0.0f, z = 0.0f;
        #pragma unroll
        for (int i = 0; i < 16; ++i) tg += ws[i];
        #pragma unroll
        for (int i = 0; i < 32; ++i) z += ws[16 + i];
        out[0] = (z - tg) / (float)BATCH;
    }
}

extern "C" void kernel_launch(void* const* d_in, const int* in_sizes, int n_in,
                              void* d_out, int out_size, void* d_ws, size_t ws_size,
                              hipStream_t stream) {
    const float* scores = (const float*)d_in[0];
    const int*   target = (const int*)d_in[1];
    const int*   mask   = (const int*)d_in[2];
    float* out  = (float*)d_out;
    float* ws   = (float*)d_ws;
    float* Qbuf = (float*)((char*)d_ws + 2048);
    int*   ctr  = (int*)((char*)d_ws + 2048 + (size_t)BATCH*2048*sizeof(float));
    const size_t need = 2048 + (size_t)BATCH*2048*sizeof(float) + (size_t)NPAIR*BATCH*sizeof(int);

    tg_kernel<<<16, 256, 0, stream>>>(scores, target, mask, ws);
    if (ws_size >= need) {
        init_fused<<<BATCH, 1024, 0, stream>>>(scores, Qbuf, ctr);
        scan_fused<<<BATCH * 8, 384, 0, stream>>>(scores, mask, Qbuf, ctr);
        finalize_fused<<<1, 64, 0, stream>>>(ws, Qbuf, mask, out);
    } else {
        scan_simple<<<BATCH, 1024, 0, stream>>>(scores, mask, ws);
        finalize_simple<<<1, 64, 0, stream>>>(ws, out);
    }
}

// Round 5
// 371.172 us; speedup vs baseline: 4.0612x; 4.0612x over previous
//
#include <hip/hip_runtime.h>
#include <hip/hip_bf16.h>
#include <math.h>

#define SEQ_LEN 128
#define BATCH   32
#define T       32
#define TT      (T*T)     // 1024
#define TTT     (T*T*T)   // 32768
#define START   30
#define END     31

#define LOG2E   1.44269504088896f
#define OFF4    5.77078016355587f   // 4 * log2(e)

// raw per-step barrier: drain LDS ops only; global prefetch stays in flight
#define BLOCK_SYNC() do {                                   \
    asm volatile("s_waitcnt lgkmcnt(0)" ::: "memory");      \
    __builtin_amdgcn_sched_barrier(0);                      \
    __builtin_amdgcn_s_barrier();                           \
    __builtin_amdgcn_sched_barrier(0);                      \
} while (0)

// ---------------------------------------------------------------------------
// Kernel 1: tg_energy gather. ws[0..15] <- per-block partial sums.
// ---------------------------------------------------------------------------
__global__ __launch_bounds__(256) void tg_kernel(const float* __restrict__ scores,
                                                 const int*   __restrict__ target,
                                                 const int*   __restrict__ mask,
                                                 float*       __restrict__ ws) {
    int idx = blockIdx.x * 256 + threadIdx.x;   // idx = s*BATCH + b
    float v = 0.0f;
    if (mask[idx] != 0) {
        v = scores[(size_t)idx * TTT + target[idx]];
    }
    #pragma unroll
    for (int off = 32; off > 0; off >>= 1)
        v += __shfl_down(v, off, 64);
    __shared__ float partial[4];
    int wave = threadIdx.x >> 6;
    int lane = threadIdx.x & 63;
    if (lane == 0) partial[wave] = v;
    __syncthreads();
    if (threadIdx.x == 0)
        ws[blockIdx.x] = partial[0] + partial[1] + partial[2] + partial[3];
}

// ---------------------------------------------------------------------------
// Kernel 2: single-block-per-batch linear-domain scan, register-prefetched.
// 32 blocks x 1024 threads. Thread = (j, k4, h):
//   j  = wave*2 + ((lane>>3)&1)   output row
//   k4 = lane&7                   output quad (k = 4*k4..4*k4+4)
//   h  = lane>>4                  i-subrange [8h, 8h+8)
// Per step: Q_t[j,k] = sum_i exp(S_t[i,j,k] - 4) * Q_{t-1}[i,j]
// Reduce over h via shfl_xor(16|32). One raw s_barrier per step.
// ws[16+b] <- 4*(#active steps) + log(Q_127[END,END])
// ---------------------------------------------------------------------------
__global__ __launch_bounds__(1024) void scan_fast(const float* __restrict__ scores,
                                                  const int*   __restrict__ maskI,
                                                  float*       __restrict__ ws) {
    const int b    = blockIdx.x;
    const int tid  = threadIdx.x;
    const int w    = tid >> 6;
    const int lane = tid & 63;
    const int h    = lane >> 4;
    const int jp   = (lane >> 3) & 1;
    const int k4   = lane & 7;
    const int j    = w * 2 + jp;

    __shared__ float Q[2][TT];
    __shared__ int   lmask[SEQ_LEN];

    if (tid < SEQ_LEN) lmask[tid] = maskI[tid * BATCH + b];

    // init: Q[1][x,y] = exp(p1[x] + s1[x,y])
    {
        int x = tid >> 5, y = tid & 31;
        float p1 = scores[(size_t)(0*BATCH + b)*TTT + START*TT + START*T + x];
        float s1 = scores[(size_t)(1*BATCH + b)*TTT + START*TT + x*T + y];
        Q[1][x*T + y] = __expf(p1 + s1);
    }
    __syncthreads();

    const int loff = h*8*TT + j*T + k4*4;   // float offset within a step slab

    float4 SA[8], SB[8];

    auto issue = [&](float4 (&S)[8], int t) {
        const float* p = scores + ((size_t)t*BATCH + b)*TTT + loff;
        #pragma unroll
        for (int m = 0; m < 8; ++m) S[m] = *(const float4*)(p + m*TT);
    };

    auto process = [&](float4 (&S)[8], int t) {
        const float* qc = Q[(t-1) & 1];
        float*       qn = Q[t & 1];

        // E = exp(S - 4) = 2^(S*log2e - 4log2e): off the Q dependency chain
        #pragma unroll
        for (int m = 0; m < 8; ++m) {
            S[m].x = exp2f(fmaf(S[m].x, LOG2E, -OFF4));
            S[m].y = exp2f(fmaf(S[m].y, LOG2E, -OFF4));
            S[m].z = exp2f(fmaf(S[m].z, LOG2E, -OFF4));
            S[m].w = exp2f(fmaf(S[m].w, LOG2E, -OFF4));
        }
        float4 acc = make_float4(0.f, 0.f, 0.f, 0.f);
        #pragma unroll
        for (int m = 0; m < 8; ++m) {
            float q = qc[(h*8 + m)*T + j];
            acc.x = fmaf(S[m].x, q, acc.x);
            acc.y = fmaf(S[m].y, q, acc.y);
            acc.z = fmaf(S[m].z, q, acc.z);
            acc.w = fmaf(S[m].w, q, acc.w);
        }
        // reduce over h (lane bits 4 and 5)
        acc.x += __shfl_xor(acc.x, 16, 64);
        acc.y += __shfl_xor(acc.y, 16, 64);
        acc.z += __shfl_xor(acc.z, 16, 64);
        acc.w += __shfl_xor(acc.w, 16, 64);
        acc.x += __shfl_xor(acc.x, 32, 64);
        acc.y += __shfl_xor(acc.y, 32, 64);
        acc.z += __shfl_xor(acc.z, 32, 64);
        acc.w += __shfl_xor(acc.w, 32, 64);

        if (lane < 16) {
            if (lmask[t] != 0) {
                *(float4*)&qn[j*T + k4*4] = acc;
            } else {
                *(float4*)&qn[j*T + k4*4] = *(const float4*)&qc[j*T + k4*4];
            }
        }
        BLOCK_SYNC();
    };

    issue(SA, 2);
    for (int t = 2; t < SEQ_LEN; t += 2) {
        issue(SB, t + 1);          // t+1 <= 127 always (t <= 126)
        process(SA, t);
        if (t + 2 < SEQ_LEN) issue(SA, t + 2);
        process(SB, t + 1);
    }

    if (tid == 0) {
        int cnt = 0;
        for (int t = 2; t < SEQ_LEN; ++t) cnt += (lmask[t] != 0);
        ws[16 + b] = 4.0f * (float)cnt + logf(Q[1][END*T + END]);
    }
}

// ---------------------------------------------------------------------------
// Kernel 3: finalize. out = (z - tg_energy) / BATCH
// ---------------------------------------------------------------------------
__global__ void finalize_kernel(const float* __restrict__ ws, float* __restrict__ out) {
    if (threadIdx.x == 0) {
        float tg = 0.0f, z = 0.0f;
        #pragma unroll
        for (int i = 0; i < 16; ++i) tg += ws[i];
        #pragma unroll
        for (int i = 0; i < 32; ++i) z += ws[16 + i];
        out[0] = (z - tg) / (float)BATCH;
    }
}

extern "C" void kernel_launch(void* const* d_in, const int* in_sizes, int n_in,
                              void* d_out, int out_size, void* d_ws, size_t ws_size,
                              hipStream_t stream) {
    const float* scores = (const float*)d_in[0];
    const int*   target = (const int*)d_in[1];
    const int*   mask   = (const int*)d_in[2];
    float* out = (float*)d_out;
    float* ws  = (float*)d_ws;

    tg_kernel<<<16, 256, 0, stream>>>(scores, target, mask, ws);
    scan_fast<<<BATCH, 1024, 0, stream>>>(scores, mask, ws);
    finalize_kernel<<<1, 64, 0, stream>>>(ws, out);
}